// Round 10
// baseline (173.898 us; speedup 1.0000x reference)
//
#include <hip/hip_runtime.h>
#include <math.h>

// Problem constants (B,K,N,M) = (32,128,128,256)
#define Bb 32
#define Kk 128
#define Nn 128
#define Mm 256
#define EPS2 0.01f      // EPSILON^2
#define LAMBDA_S 0.1f
#define LR 0.01f
#define BN_EPS_C 1e-5f

#define SWZ(c) (((c) & 14) | (((c) & 1) << 4) | (((c) >> 4) & 1))

__device__ __forceinline__ float readlane_f(float v, int lane) {
  return __int_as_float(__builtin_amdgcn_readlane(__float_as_int(v), lane));
}

// ---------------------------------------------------------------------------
// kA: fused BatchNorm (blocks 0..127, x kept in regs) + Psum (blocks 128..191).
__global__ void kA_bn_psum(const float* __restrict__ x, const float* __restrict__ P,
                           float* __restrict__ xn, float* __restrict__ Psum) {
  int t = threadIdx.x;
  if (blockIdx.x < 128) {
    int n = blockIdx.x;
    float v[32];
    float s = 0.f, s2 = 0.f;
    #pragma unroll
    for (int b = 0; b < Bb; ++b) {
      v[b] = x[(size_t)b * (Nn * Mm) + n * Mm + t];
      s += v[b];
      s2 += v[b] * v[b];
    }
    #pragma unroll
    for (int o = 32; o > 0; o >>= 1) {
      s += __shfl_down(s, o, 64);
      s2 += __shfl_down(s2, o, 64);
    }
    __shared__ float rs[4], rs2[4];
    if ((t & 63) == 0) { rs[t >> 6] = s; rs2[t >> 6] = s2; }
    __syncthreads();
    float S = rs[0] + rs[1] + rs[2] + rs[3];
    float S2 = rs2[0] + rs2[1] + rs2[2] + rs2[3];
    float mean = S * (1.0f / (Bb * Mm));
    float var = S2 * (1.0f / (Bb * Mm)) - mean * mean;
    float rstd = 1.0f / sqrtf(var + BN_EPS_C);
    #pragma unroll
    for (int b = 0; b < Bb; ++b)
      xn[(size_t)b * (Nn * Mm) + n * Mm + t] = (v[b] - mean) * rstd;
  } else {
    int e = (blockIdx.x - 128) * 256 + t;
    float s = 0.f;
    #pragma unroll 8
    for (int k = 0; k < Kk; ++k) s += P[(size_t)k * 16384 + e];
    Psum[e] = s;
  }
}

// ---------------------------------------------------------------------------
// k3S v2: 512-thread blocks (2 waves/SIMD hide LDS latency).
// blocks 0..128: blocked GJ inverse (nb=16), 4x8 register tiles/thread.
//   Phase B broadcast via readlane (SGPR) + rcp/Newton pivot reciprocal.
// blocks 129..160: S_b = xn_b xn_b^T, one b per block.
// grid 161, block 512.
__global__ __launch_bounds__(512, 1) void k3S(
    const float* __restrict__ P, const float* __restrict__ Psum,
    const float* __restrict__ cnt, float* __restrict__ C,
    const float* __restrict__ xn, float* __restrict__ S) {
  __shared__ __align__(16) float LB[8448];
  int bx = blockIdx.x;
  int t = threadIdx.x;

  if (bx < 129) {
    float* Mt = LB;            // 16*132 = 2112
    float* Rb = LB + 2112;     // 16*128 = 2048
    float* redc = LB + 4160;   // 8
    int blk = bx;
    int tx = t & 15;           // col octet: cols tx*8..tx*8+7
    int ty = t >> 4;           // 0..31: rows ty*4..ty*4+3

    float cv = cnt[t & 127];
    float sr = cv;
    #pragma unroll
    for (int o = 32; o > 0; o >>= 1) sr += __shfl_down(sr, o, 64);
    if ((t & 63) == 0 && t < 128) redc[t >> 6] = sr;
    __syncthreads();
    float total = redc[0] + redc[1];
    bool has = total > 1e-6f;
    float av;
    if (blk < 128) {
      float c = cnt[blk];
      float bk = (c != 0.0f) ? 1.0f : 0.0f;
      float cfix = c + (1.0f - bk);
      av = (float)Nn / (cfix * EPS2) * bk;
    } else {
      av = has ? ((float)Nn / (EPS2 * total)) : 0.0f;
    }
    const float* src = (blk < 128) ? (P + (size_t)blk * 16384) : Psum;

    // init a = av*src + I ; rows ty*4+i, cols tx*8..+7
    float a[4][8];
    #pragma unroll
    for (int i = 0; i < 4; ++i) {
      int row = ty * 4 + i;
      float4 p0 = *(const float4*)&src[row * 128 + tx * 8];
      float4 p1 = *(const float4*)&src[row * 128 + tx * 8 + 4];
      a[i][0] = av * p0.x; a[i][1] = av * p0.y; a[i][2] = av * p0.z; a[i][3] = av * p0.w;
      a[i][4] = av * p1.x; a[i][5] = av * p1.y; a[i][6] = av * p1.z; a[i][7] = av * p1.w;
      if (tx == (ty >> 1)) a[i][(ty & 1) * 4 + i] += 1.0f;
    }

    for (int kb = 0; kb < 8; ++kb) {
      int k0 = kb * 16;
      if ((ty >> 2) == kb) {          // R dump: pre-panel pivot rows, swizzled
        int d = (ty & 3) * 4;
        #pragma unroll
        for (int i = 0; i < 4; ++i) {
          *(float4*)&Rb[(d + i) * 128 + SWZ(2 * tx) * 4] =
              make_float4(a[i][0], a[i][1], a[i][2], a[i][3]);
          *(float4*)&Rb[(d + i) * 128 + SWZ(2 * tx + 1) * 4] =
              make_float4(a[i][4], a[i][5], a[i][6], a[i][7]);
        }
      }
      if ((tx >> 1) == kb) {          // M dump, transposed, quad over rows
        int dh = tx & 1;
        #pragma unroll
        for (int j = 0; j < 8; ++j)
          *(float4*)&Mt[(dh * 8 + j) * 132 + ty * 4] =
              make_float4(a[0][j], a[1][j], a[2][j], a[3][j]);
      }
      __syncthreads();

      if (t < 64) {                   // wave 0 factors the 128x16 panel
        int l = t;
        float m[2][16];
        #pragma unroll
        for (int d = 0; d < 2; ++d)
          #pragma unroll
          for (int j = 0; j < 16; ++j)
            m[d][j] = Mt[j * 132 + 2 * l + d];
        #pragma unroll
        for (int q = 0; q < 16; ++q) {
          int lq = (k0 + q) >> 1;     // wave-uniform owner lane
          float pr[16];
          #pragma unroll
          for (int j = 0; j < 16; ++j) pr[j] = readlane_f(m[q & 1][j], lq);
          float piv = pr[q];
          float r0 = __builtin_amdgcn_rcpf(piv);
          float pinv = r0 * (2.0f - piv * r0);   // Newton -> ~fp32-exact
          #pragma unroll
          for (int d = 0; d < 2; ++d) {
            float f = m[d][q];
            bool isp = (2 * l + d == k0 + q);
            float g = isp ? (1.0f - pinv) : f * pinv;
            #pragma unroll
            for (int j = 0; j < 16; ++j) m[d][j] = fmaf(-g, pr[j], m[d][j]);
            m[d][q] = isp ? pinv : -g;
          }
        }
        #pragma unroll
        for (int d = 0; d < 2; ++d)
          #pragma unroll
          for (int j = 0; j < 16; ++j)
            Mt[j * 132 + 2 * l + d] = m[d][j];
      }
      __syncthreads();

      if ((ty >> 2) == kb) {          // panel rows: old value dropped
        #pragma unroll
        for (int i = 0; i < 4; ++i)
          #pragma unroll
          for (int j = 0; j < 8; ++j) a[i][j] = 0.0f;
      }
      #pragma unroll
      for (int q = 0; q < 16; ++q) {  // rank-16 trailing update
        float4 mq4 = *(const float4*)&Mt[q * 132 + ty * 4];
        float4 r0q = *(const float4*)&Rb[q * 128 + SWZ(2 * tx) * 4];
        float4 r1q = *(const float4*)&Rb[q * 128 + SWZ(2 * tx + 1) * 4];
        float mq[4] = {mq4.x, mq4.y, mq4.z, mq4.w};
        float rq[8] = {r0q.x, r0q.y, r0q.z, r0q.w, r1q.x, r1q.y, r1q.z, r1q.w};
        #pragma unroll
        for (int i = 0; i < 4; ++i)
          #pragma unroll
          for (int j = 0; j < 8; ++j)
            a[i][j] = fmaf(mq[i], rq[j], a[i][j]);
      }
      if ((tx >> 1) == kb) {          // panel cols: value IS M (reload)
        int dh = tx & 1;
        #pragma unroll
        for (int j = 0; j < 8; ++j) {
          float4 v = *(const float4*)&Mt[(dh * 8 + j) * 132 + ty * 4];
          a[0][j] = v.x; a[1][j] = v.y; a[2][j] = v.z; a[3][j] = v.w;
        }
      }
      __syncthreads();
    }

    float* dst = C + (size_t)blk * 16384;
    #pragma unroll
    for (int i = 0; i < 4; ++i) {
      int row = ty * 4 + i;
      float4 v0 = make_float4(av * a[i][0], av * a[i][1], av * a[i][2], av * a[i][3]);
      float4 v1 = make_float4(av * a[i][4], av * a[i][5], av * a[i][6], av * a[i][7]);
      *(float4*)&dst[row * 128 + tx * 8] = v0;
      *(float4*)&dst[row * 128 + tx * 8 + 4] = v1;
    }
  } else {
    // ---- S branch: S_b = xn_b xn_b^T, one b per block, 512 threads ----
    int b = bx - 129;
    float* X = LB;  // 128*65 = 8320 floats
    int tx = t & 15, ty = t >> 4;     // out tile: rows ty*4..+3, cols tx*8..+7
    float acc[4][8] = {};
    for (int mc = 0; mc < Mm; mc += 64) {
      __syncthreads();
      #pragma unroll
      for (int c = 0; c < 16; ++c) {
        int e = c * 512 + t;
        int i = e >> 6, mm = e & 63;
        X[i * 65 + mm] = xn[(size_t)b * (Nn * Mm) + i * Mm + mc + mm];
      }
      __syncthreads();
      for (int mm = 0; mm < 64; ++mm) {
        float ai[4], bj[8];
        #pragma unroll
        for (int q = 0; q < 4; ++q) ai[q] = X[(ty * 4 + q) * 65 + mm];
        #pragma unroll
        for (int q = 0; q < 8; ++q) bj[q] = X[(tx * 8 + q) * 65 + mm];
        #pragma unroll
        for (int qi = 0; qi < 4; ++qi)
          #pragma unroll
          for (int qj = 0; qj < 8; ++qj)
            acc[qi][qj] = fmaf(ai[qi], bj[qj], acc[qi][qj]);
      }
    }
    float* dst = S + (size_t)b * 16384;
    #pragma unroll
    for (int qi = 0; qi < 4; ++qi) {
      *(float4*)&dst[(ty * 4 + qi) * 128 + tx * 8] =
          make_float4(acc[qi][0], acc[qi][1], acc[qi][2], acc[qi][3]);
      *(float4*)&dst[(ty * 4 + qi) * 128 + tx * 8 + 4] =
          make_float4(acc[qi][4], acc[qi][5], acc[qi][6], acc[qi][7]);
    }
  }
}

// ---------------------------------------------------------------------------
// kGN: fused gram + Frobenius inner products. grid 256 = (k, j-half).
__global__ __launch_bounds__(256, 1) void kGN(const float* __restrict__ C,
                                              const float* __restrict__ S,
                                              float* __restrict__ norm2h) {
  __shared__ __align__(16) float LB[128 * 128];  // 64 KB
  __shared__ float redb[4][32];
  int k = blockIdx.x >> 1, h = blockIdx.x & 1;
  int t = threadIdx.x;
  const float* src = C + (size_t)k * 16384;
  for (int c = 0; c < 64; ++c) LB[c * 256 + t] = src[c * 256 + t];
  __syncthreads();
  int tx = t & 15, ty = t >> 4;
  int i0 = ty * 8, j0 = h * 64 + tx * 4;
  float acc[8][4] = {};
  for (int l = 0; l < 128; ++l) {
    float ai[8], bj[4];
    *(float4*)&ai[0] = *(const float4*)&LB[l * 128 + i0];
    *(float4*)&ai[4] = *(const float4*)&LB[l * 128 + i0 + 4];
    *(float4*)&bj[0] = *(const float4*)&LB[l * 128 + j0];
    #pragma unroll
    for (int qi = 0; qi < 8; ++qi)
      #pragma unroll
      for (int qj = 0; qj < 4; ++qj)
        acc[qi][qj] = fmaf(ai[qi], bj[qj], acc[qi][qj]);
  }
  __syncthreads();
  #pragma unroll
  for (int qi = 0; qi < 8; ++qi)
    *(float4*)&LB[(i0 + qi) * 64 + tx * 4] =
        make_float4(acc[qi][0], acc[qi][1], acc[qi][2], acc[qi][3]);
  __syncthreads();
  float nacc[32];
  #pragma unroll
  for (int b = 0; b < 32; ++b) nacc[b] = 0.0f;
  #pragma unroll
  for (int q = 0; q < 8; ++q) {
    int el = (q * 256 + t) * 4;
    float4 g = *(const float4*)&LB[el];
    int i = el >> 6, jl = el & 63;
    const float* sb = S + i * 128 + h * 64 + jl;
    #pragma unroll
    for (int b = 0; b < 32; ++b) {
      float4 sv = *(const float4*)&sb[(size_t)b * 16384];
      nacc[b] = fmaf(g.x, sv.x, nacc[b]);
      nacc[b] = fmaf(g.y, sv.y, nacc[b]);
      nacc[b] = fmaf(g.z, sv.z, nacc[b]);
      nacc[b] = fmaf(g.w, sv.w, nacc[b]);
    }
  }
  #pragma unroll
  for (int b = 0; b < 32; ++b) {
    float v = nacc[b];
    #pragma unroll
    for (int o = 32; o > 0; o >>= 1) v += __shfl_down(v, o, 64);
    nacc[b] = v;
  }
  if ((t & 63) == 0) {
    int w = t >> 6;
    #pragma unroll
    for (int b = 0; b < 32; ++b) redb[w][b] = nacc[b];
  }
  __syncthreads();
  if (t < 32)
    norm2h[(size_t)k * 64 + h * 32 + t] =
        redb[0][t] + redb[1][t] + redb[2][t] + redb[3][t];
}

// ---------------------------------------------------------------------------
// k7n: norms -> rescale -> softmax -> wT[k][b]. grid 32, block 128.
__global__ void k7n(const float* __restrict__ norm2h, const float* __restrict__ cnt,
                    float* __restrict__ wT) {
  int b = blockIdx.x;
  int k = threadIdx.x;
  float n2 = norm2h[(size_t)k * 64 + b] + norm2h[(size_t)k * 64 + 32 + b];
  float norm = sqrtf(fmaxf(n2, 0.0f));
  float cv = cnt[k];
  __shared__ float r1[2], r2[2], r3[2];
  float tt = cv, r = norm;
  #pragma unroll
  for (int o = 32; o > 0; o >>= 1) {
    tt += __shfl_down(tt, o, 64);
    r += __shfl_down(r, o, 64);
  }
  if ((k & 63) == 0) { r1[k >> 6] = tt; r2[k >> 6] = r; }
  __syncthreads();
  float total = r1[0] + r1[1];
  float sumn = r2[0] + r2[1];
  float nr = 10.0f * norm / fmaxf(sumn, 1e-30f);
  float ex = expf(-LAMBDA_S * nr);
  float e2 = ex;
  #pragma unroll
  for (int o = 32; o > 0; o >>= 1) e2 += __shfl_down(e2, o, 64);
  if ((k & 63) == 0) r3[k >> 6] = e2;
  __syncthreads();
  float sume = r3[0] + r3[1];
  float bk = (cv != 0.0f) ? 1.0f : 0.0f;
  float pi = (ex / sume) * bk;
  float gama = (total > 1e-6f) ? (cv / total) : 0.0f;
  wT[k * 32 + b] = gama * pi;
}

// ---------------------------------------------------------------------------
// k8: F[b] = e - sum_k w[b][k]*c_k. grid (64,4), block 256.
__global__ __launch_bounds__(256, 1) void k8_k(const float* __restrict__ C,
                                               const float* __restrict__ E,
                                               const float* __restrict__ wT,
                                               float* __restrict__ F) {
  int e = blockIdx.x * 256 + threadIdx.x;
  int b0 = blockIdx.y * 8;
  float acc[8];
  float ev = E[e];
  #pragma unroll
  for (int b = 0; b < 8; ++b) acc[b] = ev;
  for (int k = 0; k < 128; ++k) {
    float cv = C[(size_t)k * 16384 + e];
    const float* wk = wT + k * 32 + b0;
    #pragma unroll
    for (int b = 0; b < 8; ++b) acc[b] = fmaf(-wk[b], cv, acc[b]);
  }
  #pragma unroll
  for (int b = 0; b < 8; ++b) F[(size_t)(b0 + b) * 16384 + e] = acc[b];
}

// ---------------------------------------------------------------------------
// k9: out[b] = xn[b] + LR * F[b] @ xn[b]. grid 256, block 256 (vectorized LDS).
__global__ __launch_bounds__(256, 1) void k9_k(const float* __restrict__ F,
                                               const float* __restrict__ xn,
                                               float* __restrict__ out) {
  int bx = blockIdx.x;
  int b = bx >> 3, y = bx & 7;
  int mq = y >> 1, ih = y & 1;
  __shared__ __align__(16) float Ft[64 * 68];
  __shared__ __align__(16) float Xt[64 * 68];
  int t = threadIdx.x;
  int tx = t & 15, ty = t >> 4;
  float acc[4][4] = {};
  for (int jc = 0; jc < 128; jc += 64) {
    __syncthreads();
    #pragma unroll
    for (int q = 0; q < 4; ++q) {
      int e = q * 256 + t;
      int i = e >> 4, j4 = e & 15;
      *(float4*)&Ft[i * 68 + j4 * 4] =
          *(const float4*)&F[(size_t)b * 16384 + (ih * 64 + i) * 128 + jc + j4 * 4];
    }
    #pragma unroll
    for (int q = 0; q < 4; ++q) {
      int e = q * 256 + t;
      int jj = e >> 4, m4 = e & 15;
      *(float4*)&Xt[jj * 68 + m4 * 4] =
          *(const float4*)&xn[(size_t)b * (Nn * Mm) + (jc + jj) * Mm + mq * 64 + m4 * 4];
    }
    __syncthreads();
    for (int j4 = 0; j4 < 16; ++j4) {
      float4 fi[4], xm[4];
      #pragma unroll
      for (int r = 0; r < 4; ++r)
        fi[r] = *(const float4*)&Ft[(ty * 4 + r) * 68 + j4 * 4];
      #pragma unroll
      for (int r = 0; r < 4; ++r)
        xm[r] = *(const float4*)&Xt[(j4 * 4 + r) * 68 + tx * 4];
      #pragma unroll
      for (int qi = 0; qi < 4; ++qi) {
        #pragma unroll
        for (int qm = 0; qm < 4; ++qm) {
          float xv = ((const float*)&xm[0])[qm];
          acc[qi][qm] = fmaf(fi[qi].x, xv, acc[qi][qm]);
          xv = ((const float*)&xm[1])[qm];
          acc[qi][qm] = fmaf(fi[qi].y, xv, acc[qi][qm]);
          xv = ((const float*)&xm[2])[qm];
          acc[qi][qm] = fmaf(fi[qi].z, xv, acc[qi][qm]);
          xv = ((const float*)&xm[3])[qm];
          acc[qi][qm] = fmaf(fi[qi].w, xv, acc[qi][qm]);
        }
      }
    }
  }
  int i0 = ih * 64 + ty * 4, m0 = mq * 64 + tx * 4;
  #pragma unroll
  for (int qi = 0; qi < 4; ++qi) {
    float4 xv = *(const float4*)&xn[(size_t)b * (Nn * Mm) + (i0 + qi) * Mm + m0];
    float4 o;
    o.x = fmaf(LR, acc[qi][0], xv.x);
    o.y = fmaf(LR, acc[qi][1], xv.y);
    o.z = fmaf(LR, acc[qi][2], xv.z);
    o.w = fmaf(LR, acc[qi][3], xv.w);
    *(float4*)&out[(size_t)b * (Nn * Mm) + (i0 + qi) * Mm + m0] = o;
  }
}

// ---------------------------------------------------------------------------
extern "C" void kernel_launch(void* const* d_in, const int* in_sizes, int n_in,
                              void* d_out, int out_size, void* d_ws, size_t ws_size,
                              hipStream_t stream) {
  const float* x = (const float*)d_in[0];     // (32,128,256)
  const float* P = (const float*)d_in[1];     // (128,128,128) EC_proto
  const float* cnt = (const float*)d_in[2];   // (128,)
  float* out = (float*)d_out;

  float* ws = (float*)d_ws;
  float* xn = ws;                               // 1048576
  float* C = xn + 1048576;                      // 129*16384 (c_k; slot 128 = e)
  float* S = C + 2113536;                       // 524288
  float* norm2h = S + 524288;                   // 8192
  float* wT = norm2h + 8192;                    // 4096
  float* F = wT + 4096;                         // 524288
  float* Psum = F + 524288;                     // 16384
  size_t need_bytes = (size_t)((Psum + 16384) - ws) * sizeof(float);
  if (ws_size < need_bytes) return;  // ~17 MB required

  hipLaunchKernelGGL(kA_bn_psum, dim3(192), dim3(256), 0, stream, x, P, xn, Psum);
  hipLaunchKernelGGL(k3S, dim3(161), dim3(512), 0, stream, P, Psum, cnt, C, xn, S);
  hipLaunchKernelGGL(kGN, dim3(256), dim3(256), 0, stream, C, S, norm2h);
  hipLaunchKernelGGL(k7n, dim3(32), dim3(128), 0, stream, norm2h, cnt, wT);
  hipLaunchKernelGGL(k8_k, dim3(64, 4), dim3(256), 0, stream, C,
                     C + (size_t)128 * 16384, wT, F);
  hipLaunchKernelGGL(k9_k, dim3(256), dim3(256), 0, stream, F, xn, out);
}

// Round 11
// 163.542 us; speedup vs baseline: 1.0633x; 1.0633x over previous
//
#include <hip/hip_runtime.h>
#include <math.h>

// Problem constants (B,K,N,M) = (32,128,128,256)
#define Bb 32
#define Kk 128
#define Nn 128
#define Mm 256
#define EPS2 0.01f      // EPSILON^2
#define LAMBDA_S 0.1f
#define LR 0.01f
#define BN_EPS_C 1e-5f

#define SWZ(c) (((c) & 14) | (((c) & 1) << 4) | (((c) >> 4) & 1))

__device__ __forceinline__ float readlane_f(float v, int lane) {
  return __int_as_float(__builtin_amdgcn_readlane(__float_as_int(v), lane));
}

// ---------------------------------------------------------------------------
// kA: fused BatchNorm (blocks 0..127, x kept in regs) + Psum (blocks 128..191).
__global__ void kA_bn_psum(const float* __restrict__ x, const float* __restrict__ P,
                           float* __restrict__ xn, float* __restrict__ Psum) {
  int t = threadIdx.x;
  if (blockIdx.x < 128) {
    int n = blockIdx.x;
    float v[32];
    float s = 0.f, s2 = 0.f;
    #pragma unroll
    for (int b = 0; b < Bb; ++b) {
      v[b] = x[(size_t)b * (Nn * Mm) + n * Mm + t];
      s += v[b];
      s2 += v[b] * v[b];
    }
    #pragma unroll
    for (int o = 32; o > 0; o >>= 1) {
      s += __shfl_down(s, o, 64);
      s2 += __shfl_down(s2, o, 64);
    }
    __shared__ float rs[4], rs2[4];
    if ((t & 63) == 0) { rs[t >> 6] = s; rs2[t >> 6] = s2; }
    __syncthreads();
    float S = rs[0] + rs[1] + rs[2] + rs[3];
    float S2 = rs2[0] + rs2[1] + rs2[2] + rs2[3];
    float mean = S * (1.0f / (Bb * Mm));
    float var = S2 * (1.0f / (Bb * Mm)) - mean * mean;
    float rstd = 1.0f / sqrtf(var + BN_EPS_C);
    #pragma unroll
    for (int b = 0; b < Bb; ++b)
      xn[(size_t)b * (Nn * Mm) + n * Mm + t] = (v[b] - mean) * rstd;
  } else {
    int e = (blockIdx.x - 128) * 256 + t;
    float s = 0.f;
    #pragma unroll 8
    for (int k = 0; k < Kk; ++k) s += P[(size_t)k * 16384 + e];
    Psum[e] = s;
  }
}

// ---------------------------------------------------------------------------
// k3S (R9 geometry + readlane/rcp phase B): blocks 0..128 = blocked GJ inverse
// (nb=16, 8x8 reg tiles, 256 threads); blocks 129..192 = S_b = xn_b xn_b^T.
// grid 193, block 256.
__global__ __launch_bounds__(256, 1) void k3S(
    const float* __restrict__ P, const float* __restrict__ Psum,
    const float* __restrict__ cnt, float* __restrict__ C,
    const float* __restrict__ xn, float* __restrict__ S) {
  __shared__ __align__(16) float LB[8448];
  int bx = blockIdx.x;
  int t = threadIdx.x;

  if (bx < 129) {
    float* Mt = LB;            // 16*132 = 2112
    float* Rb = LB + 2112;     // 16*128 = 2048
    float* redc = LB + 4160;   // 4
    int blk = bx;
    int tx = t & 15, ty = t >> 4;

    float cv = cnt[t & 127];
    float sr = cv;
    #pragma unroll
    for (int o = 32; o > 0; o >>= 1) sr += __shfl_down(sr, o, 64);
    if ((t & 63) == 0) redc[t >> 6] = sr;
    __syncthreads();
    float total = redc[0] + redc[1];
    bool has = total > 1e-6f;
    float av;
    if (blk < 128) {
      float c = cnt[blk];
      float bk = (c != 0.0f) ? 1.0f : 0.0f;
      float cfix = c + (1.0f - bk);
      av = (float)Nn / (cfix * EPS2) * bk;
    } else {
      av = has ? ((float)Nn / (EPS2 * total)) : 0.0f;
    }
    const float* src = (blk < 128) ? (P + (size_t)blk * 16384) : Psum;

    float a[8][8];
    #pragma unroll
    for (int i = 0; i < 8; ++i) {
      int row = ty * 8 + i;
      float4 p0 = *(const float4*)&src[row * 128 + tx * 8];
      float4 p1 = *(const float4*)&src[row * 128 + tx * 8 + 4];
      a[i][0] = av * p0.x; a[i][1] = av * p0.y; a[i][2] = av * p0.z; a[i][3] = av * p0.w;
      a[i][4] = av * p1.x; a[i][5] = av * p1.y; a[i][6] = av * p1.z; a[i][7] = av * p1.w;
      if (tx == ty) a[i][i] += 1.0f;
    }

    for (int kb = 0; kb < 8; ++kb) {
      int k0 = kb * 16;
      if ((ty >> 1) == kb) {          // R dump (swizzled, conflict-free)
        int d = ty & 1;
        #pragma unroll
        for (int i = 0; i < 8; ++i) {
          *(float4*)&Rb[(d * 8 + i) * 128 + SWZ(2 * tx) * 4] =
              make_float4(a[i][0], a[i][1], a[i][2], a[i][3]);
          *(float4*)&Rb[(d * 8 + i) * 128 + SWZ(2 * tx + 1) * 4] =
              make_float4(a[i][4], a[i][5], a[i][6], a[i][7]);
        }
      }
      if ((tx >> 1) == kb) {          // M dump (transposed)
        int dh = tx & 1;
        #pragma unroll
        for (int i = 0; i < 8; ++i)
          #pragma unroll
          for (int j = 0; j < 8; ++j)
            Mt[(dh * 8 + j) * 132 + ty * 8 + i] = a[i][j];
      }
      __syncthreads();

      if (t < 64) {                   // wave 0 factors the 128x16 panel
        int l = t;
        float m[2][16];
        #pragma unroll
        for (int d = 0; d < 2; ++d)
          #pragma unroll
          for (int j = 0; j < 16; ++j)
            m[d][j] = Mt[j * 132 + 2 * l + d];
        #pragma unroll
        for (int q = 0; q < 16; ++q) {
          int lq = (k0 + q) >> 1;     // wave-uniform owner lane
          float pr[16];
          #pragma unroll
          for (int j = 0; j < 16; ++j) pr[j] = readlane_f(m[q & 1][j], lq);
          float piv = pr[q];
          float r0 = __builtin_amdgcn_rcpf(piv);
          float pinv = r0 * (2.0f - piv * r0);   // Newton -> ~fp32-exact
          #pragma unroll
          for (int d = 0; d < 2; ++d) {
            float f = m[d][q];
            bool isp = (2 * l + d == k0 + q);
            float g = isp ? (1.0f - pinv) : f * pinv;
            #pragma unroll
            for (int j = 0; j < 16; ++j) m[d][j] = fmaf(-g, pr[j], m[d][j]);
            m[d][q] = isp ? pinv : -g;
          }
        }
        #pragma unroll
        for (int d = 0; d < 2; ++d)
          #pragma unroll
          for (int j = 0; j < 16; ++j)
            Mt[j * 132 + 2 * l + d] = m[d][j];
      }
      __syncthreads();

      if ((ty >> 1) == kb) {          // rank-16 trailing update
        #pragma unroll
        for (int i = 0; i < 8; ++i)
          #pragma unroll
          for (int j = 0; j < 8; ++j) a[i][j] = 0.0f;
      }
      #pragma unroll
      for (int q = 0; q < 16; ++q) {
        float4 m0 = *(const float4*)&Mt[q * 132 + ty * 8];
        float4 m1 = *(const float4*)&Mt[q * 132 + ty * 8 + 4];
        float4 r0 = *(const float4*)&Rb[q * 128 + SWZ(2 * tx) * 4];
        float4 r1 = *(const float4*)&Rb[q * 128 + SWZ(2 * tx + 1) * 4];
        float mq[8] = {m0.x, m0.y, m0.z, m0.w, m1.x, m1.y, m1.z, m1.w};
        float rq[8] = {r0.x, r0.y, r0.z, r0.w, r1.x, r1.y, r1.z, r1.w};
        #pragma unroll
        for (int i = 0; i < 8; ++i)
          #pragma unroll
          for (int j = 0; j < 8; ++j)
            a[i][j] = fmaf(mq[i], rq[j], a[i][j]);
      }
      if ((tx >> 1) == kb) {          // panel cols reload M
        int dh = tx & 1;
        #pragma unroll
        for (int j = 0; j < 8; ++j) {
          float4 v0 = *(const float4*)&Mt[(dh * 8 + j) * 132 + ty * 8];
          float4 v1 = *(const float4*)&Mt[(dh * 8 + j) * 132 + ty * 8 + 4];
          a[0][j] = v0.x; a[1][j] = v0.y; a[2][j] = v0.z; a[3][j] = v0.w;
          a[4][j] = v1.x; a[5][j] = v1.y; a[6][j] = v1.z; a[7][j] = v1.w;
        }
      }
      __syncthreads();
    }

    float* dst = C + (size_t)blk * 16384;
    #pragma unroll
    for (int i = 0; i < 8; ++i) {
      int row = ty * 8 + i;
      float4 v0 = make_float4(av * a[i][0], av * a[i][1], av * a[i][2], av * a[i][3]);
      float4 v1 = make_float4(av * a[i][4], av * a[i][5], av * a[i][6], av * a[i][7]);
      *(float4*)&dst[row * 128 + tx * 8] = v0;
      *(float4*)&dst[row * 128 + tx * 8 + 4] = v1;
    }
  } else {
    // ---- S branch: S_b = xn_b xn_b^T (b = bxx>>1, col-half = bxx&1) ----
    int bxx = bx - 129;
    int b = bxx >> 1;
    int jbase = (bxx & 1) * 64;
    float* X = LB;  // 128*65 = 8320 floats
    int tx = t & 15, ty = t >> 4;
    float acc[8][4] = {};
    for (int mc = 0; mc < Mm; mc += 64) {
      __syncthreads();
      for (int c = 0; c < 32; ++c) {
        int e = c * 256 + t;
        int i = e >> 6, mm = e & 63;
        X[i * 65 + mm] = xn[(size_t)b * (Nn * Mm) + i * Mm + mc + mm];
      }
      __syncthreads();
      for (int mm = 0; mm < 64; ++mm) {
        float ai[8], bj[4];
        #pragma unroll
        for (int q = 0; q < 8; ++q) ai[q] = X[(ty * 8 + q) * 65 + mm];
        #pragma unroll
        for (int q = 0; q < 4; ++q) bj[q] = X[(jbase + tx * 4 + q) * 65 + mm];
        #pragma unroll
        for (int qi = 0; qi < 8; ++qi)
          #pragma unroll
          for (int qj = 0; qj < 4; ++qj)
            acc[qi][qj] = fmaf(ai[qi], bj[qj], acc[qi][qj]);
      }
    }
    float* dst = S + (size_t)b * 16384;
    #pragma unroll
    for (int qi = 0; qi < 8; ++qi) {
      float4 v = make_float4(acc[qi][0], acc[qi][1], acc[qi][2], acc[qi][3]);
      *(float4*)&dst[(ty * 8 + qi) * 128 + jbase + tx * 4] = v;
    }
  }
}

// ---------------------------------------------------------------------------
// kGN: fused gram + Frobenius inner products. grid 256 = (k, j-half).
__global__ __launch_bounds__(256, 1) void kGN(const float* __restrict__ C,
                                              const float* __restrict__ S,
                                              float* __restrict__ norm2h) {
  __shared__ __align__(16) float LB[128 * 128];  // 64 KB
  __shared__ float redb[4][32];
  int k = blockIdx.x >> 1, h = blockIdx.x & 1;
  int t = threadIdx.x;
  const float* src = C + (size_t)k * 16384;
  for (int c = 0; c < 64; ++c) LB[c * 256 + t] = src[c * 256 + t];
  __syncthreads();
  int tx = t & 15, ty = t >> 4;
  int i0 = ty * 8, j0 = h * 64 + tx * 4;
  float acc[8][4] = {};
  for (int l = 0; l < 128; ++l) {
    float ai[8], bj[4];
    *(float4*)&ai[0] = *(const float4*)&LB[l * 128 + i0];
    *(float4*)&ai[4] = *(const float4*)&LB[l * 128 + i0 + 4];
    *(float4*)&bj[0] = *(const float4*)&LB[l * 128 + j0];
    #pragma unroll
    for (int qi = 0; qi < 8; ++qi)
      #pragma unroll
      for (int qj = 0; qj < 4; ++qj)
        acc[qi][qj] = fmaf(ai[qi], bj[qj], acc[qi][qj]);
  }
  __syncthreads();
  #pragma unroll
  for (int qi = 0; qi < 8; ++qi)
    *(float4*)&LB[(i0 + qi) * 64 + tx * 4] =
        make_float4(acc[qi][0], acc[qi][1], acc[qi][2], acc[qi][3]);
  __syncthreads();
  float nacc[32];
  #pragma unroll
  for (int b = 0; b < 32; ++b) nacc[b] = 0.0f;
  #pragma unroll
  for (int q = 0; q < 8; ++q) {
    int el = (q * 256 + t) * 4;
    float4 g = *(const float4*)&LB[el];
    int i = el >> 6, jl = el & 63;
    const float* sb = S + i * 128 + h * 64 + jl;
    #pragma unroll
    for (int b = 0; b < 32; ++b) {
      float4 sv = *(const float4*)&sb[(size_t)b * 16384];
      nacc[b] = fmaf(g.x, sv.x, nacc[b]);
      nacc[b] = fmaf(g.y, sv.y, nacc[b]);
      nacc[b] = fmaf(g.z, sv.z, nacc[b]);
      nacc[b] = fmaf(g.w, sv.w, nacc[b]);
    }
  }
  #pragma unroll
  for (int b = 0; b < 32; ++b) {
    float v = nacc[b];
    #pragma unroll
    for (int o = 32; o > 0; o >>= 1) v += __shfl_down(v, o, 64);
    nacc[b] = v;
  }
  if ((t & 63) == 0) {
    int w = t >> 6;
    #pragma unroll
    for (int b = 0; b < 32; ++b) redb[w][b] = nacc[b];
  }
  __syncthreads();
  if (t < 32)
    norm2h[(size_t)k * 64 + h * 32 + t] =
        redb[0][t] + redb[1][t] + redb[2][t] + redb[3][t];
}

// ---------------------------------------------------------------------------
// k7n: norms -> rescale -> softmax -> wT[k][b]. grid 32, block 128.
__global__ void k7n(const float* __restrict__ norm2h, const float* __restrict__ cnt,
                    float* __restrict__ wT) {
  int b = blockIdx.x;
  int k = threadIdx.x;
  float n2 = norm2h[(size_t)k * 64 + b] + norm2h[(size_t)k * 64 + 32 + b];
  float norm = sqrtf(fmaxf(n2, 0.0f));
  float cv = cnt[k];
  __shared__ float r1[2], r2[2], r3[2];
  float tt = cv, r = norm;
  #pragma unroll
  for (int o = 32; o > 0; o >>= 1) {
    tt += __shfl_down(tt, o, 64);
    r += __shfl_down(r, o, 64);
  }
  if ((k & 63) == 0) { r1[k >> 6] = tt; r2[k >> 6] = r; }
  __syncthreads();
  float total = r1[0] + r1[1];
  float sumn = r2[0] + r2[1];
  float nr = 10.0f * norm / fmaxf(sumn, 1e-30f);
  float ex = expf(-LAMBDA_S * nr);
  float e2 = ex;
  #pragma unroll
  for (int o = 32; o > 0; o >>= 1) e2 += __shfl_down(e2, o, 64);
  if ((k & 63) == 0) r3[k >> 6] = e2;
  __syncthreads();
  float sume = r3[0] + r3[1];
  float bk = (cv != 0.0f) ? 1.0f : 0.0f;
  float pi = (ex / sume) * bk;
  float gama = (total > 1e-6f) ? (cv / total) : 0.0f;
  wT[k * 32 + b] = gama * pi;
}

// ---------------------------------------------------------------------------
// k8: F[b] = e - sum_k w[b][k]*c_k. grid (64,4), block 256.
__global__ __launch_bounds__(256, 1) void k8_k(const float* __restrict__ C,
                                               const float* __restrict__ E,
                                               const float* __restrict__ wT,
                                               float* __restrict__ F) {
  int e = blockIdx.x * 256 + threadIdx.x;
  int b0 = blockIdx.y * 8;
  float acc[8];
  float ev = E[e];
  #pragma unroll
  for (int b = 0; b < 8; ++b) acc[b] = ev;
  for (int k = 0; k < 128; ++k) {
    float cv = C[(size_t)k * 16384 + e];
    const float* wk = wT + k * 32 + b0;
    #pragma unroll
    for (int b = 0; b < 8; ++b) acc[b] = fmaf(-wk[b], cv, acc[b]);
  }
  #pragma unroll
  for (int b = 0; b < 8; ++b) F[(size_t)(b0 + b) * 16384 + e] = acc[b];
}

// ---------------------------------------------------------------------------
// k9: out[b] = xn[b] + LR * F[b] @ xn[b]. grid 256, block 256 (vectorized LDS).
__global__ __launch_bounds__(256, 1) void k9_k(const float* __restrict__ F,
                                               const float* __restrict__ xn,
                                               float* __restrict__ out) {
  int bx = blockIdx.x;
  int b = bx >> 3, y = bx & 7;
  int mq = y >> 1, ih = y & 1;
  __shared__ __align__(16) float Ft[64 * 68];
  __shared__ __align__(16) float Xt[64 * 68];
  int t = threadIdx.x;
  int tx = t & 15, ty = t >> 4;
  float acc[4][4] = {};
  for (int jc = 0; jc < 128; jc += 64) {
    __syncthreads();
    #pragma unroll
    for (int q = 0; q < 4; ++q) {
      int e = q * 256 + t;
      int i = e >> 4, j4 = e & 15;
      *(float4*)&Ft[i * 68 + j4 * 4] =
          *(const float4*)&F[(size_t)b * 16384 + (ih * 64 + i) * 128 + jc + j4 * 4];
    }
    #pragma unroll
    for (int q = 0; q < 4; ++q) {
      int e = q * 256 + t;
      int jj = e >> 4, m4 = e & 15;
      *(float4*)&Xt[jj * 68 + m4 * 4] =
          *(const float4*)&xn[(size_t)b * (Nn * Mm) + (jc + jj) * Mm + mq * 64 + m4 * 4];
    }
    __syncthreads();
    for (int j4 = 0; j4 < 16; ++j4) {
      float4 fi[4], xm[4];
      #pragma unroll
      for (int r = 0; r < 4; ++r)
        fi[r] = *(const float4*)&Ft[(ty * 4 + r) * 68 + j4 * 4];
      #pragma unroll
      for (int r = 0; r < 4; ++r)
        xm[r] = *(const float4*)&Xt[(j4 * 4 + r) * 68 + tx * 4];
      #pragma unroll
      for (int qi = 0; qi < 4; ++qi) {
        #pragma unroll
        for (int qm = 0; qm < 4; ++qm) {
          float xv = ((const float*)&xm[0])[qm];
          acc[qi][qm] = fmaf(fi[qi].x, xv, acc[qi][qm]);
          xv = ((const float*)&xm[1])[qm];
          acc[qi][qm] = fmaf(fi[qi].y, xv, acc[qi][qm]);
          xv = ((const float*)&xm[2])[qm];
          acc[qi][qm] = fmaf(fi[qi].z, xv, acc[qi][qm]);
          xv = ((const float*)&xm[3])[qm];
          acc[qi][qm] = fmaf(fi[qi].w, xv, acc[qi][qm]);
        }
      }
    }
  }
  int i0 = ih * 64 + ty * 4, m0 = mq * 64 + tx * 4;
  #pragma unroll
  for (int qi = 0; qi < 4; ++qi) {
    float4 xv = *(const float4*)&xn[(size_t)b * (Nn * Mm) + (i0 + qi) * Mm + m0];
    float4 o;
    o.x = fmaf(LR, acc[qi][0], xv.x);
    o.y = fmaf(LR, acc[qi][1], xv.y);
    o.z = fmaf(LR, acc[qi][2], xv.z);
    o.w = fmaf(LR, acc[qi][3], xv.w);
    *(float4*)&out[(size_t)b * (Nn * Mm) + (i0 + qi) * Mm + m0] = o;
  }
}

// ---------------------------------------------------------------------------
extern "C" void kernel_launch(void* const* d_in, const int* in_sizes, int n_in,
                              void* d_out, int out_size, void* d_ws, size_t ws_size,
                              hipStream_t stream) {
  const float* x = (const float*)d_in[0];     // (32,128,256)
  const float* P = (const float*)d_in[1];     // (128,128,128) EC_proto
  const float* cnt = (const float*)d_in[2];   // (128,)
  float* out = (float*)d_out;

  float* ws = (float*)d_ws;
  float* xn = ws;                               // 1048576
  float* C = xn + 1048576;                      // 129*16384 (c_k; slot 128 = e)
  float* S = C + 2113536;                       // 524288
  float* norm2h = S + 524288;                   // 8192
  float* wT = norm2h + 8192;                    // 4096
  float* F = wT + 4096;                         // 524288
  float* Psum = F + 524288;                     // 16384
  size_t need_bytes = (size_t)((Psum + 16384) - ws) * sizeof(float);
  if (ws_size < need_bytes) return;  // ~17 MB required

  hipLaunchKernelGGL(kA_bn_psum, dim3(192), dim3(256), 0, stream, x, P, xn, Psum);
  hipLaunchKernelGGL(k3S, dim3(193), dim3(256), 0, stream, P, Psum, cnt, C, xn, S);
  hipLaunchKernelGGL(kGN, dim3(256), dim3(256), 0, stream, C, S, norm2h);
  hipLaunchKernelGGL(k7n, dim3(32), dim3(128), 0, stream, norm2h, cnt, wT);
  hipLaunchKernelGGL(k8_k, dim3(64, 4), dim3(256), 0, stream, C,
                     C + (size_t)128 * 16384, wT, F);
  hipLaunchKernelGGL(k9_k, dim3(256), dim3(256), 0, stream, F, xn, out);
}